// Round 4
// baseline (99.220 us; speedup 1.0000x reference)
//
#include <hip/hip_runtime.h>

#define TL 2048
#define TC 8
#define TK 84
#define TF 4
#define TD 4
#define TEXT 320              // tile: 256 outputs + 32 halo each side
#define SROW 352              // padded phase-major row stride (floats)
#define NFEAT (TD * TK * TF)  // 1344

__device__ __forceinline__ void count_one(
    int k, const float* __restrict__ l,
    const float4* __restrict__ biasL4, const float4 (*__restrict__ kwL4)[3],
    const unsigned long long* __restrict__ mokI, int d_idx,
    int (*__restrict__ feats)[TF], int lane)
{
    const float4 bq = biasL4[k];
    const float4 w0 = kwL4[k][0], w1 = kwL4[k][1], w2 = kwL4[k][2];
    const float wv[9] = {w0.x, w0.y, w0.z, w0.w, w1.x, w1.y, w1.z, w1.w, w2.x};
    const bool odd = ((d_idx + k) & 1) != 0;
    int c0 = 0, c1 = 0, c2 = 0, c3 = 0;
    #pragma unroll
    for (int i = 0; i < 4; ++i) {
        float r = 0.f;
        #pragma unroll
        for (int j = 0; j < 9; ++j) r = fmaf(wv[j], l[i + j], r);
        const unsigned long long mok = odd ? mokI[i] : ~0ull;
        c0 += __popcll(__ballot(r > bq.x) & mok);
        c1 += __popcll(__ballot(r > bq.y) & mok);
        c2 += __popcll(__ballot(r > bq.z) & mok);
        c3 += __popcll(__ballot(r > bq.w) & mok);
    }
    if (lane == 0) {
        feats[k][0] += c0; feats[k][1] += c1;
        feats[k][2] += c2; feats[k][3] += c3;
    }
}

// One 256-output tile. Phase-major Stab: ext pos e -> (e&(DIL-1))*PS + (e>>LD).
template <int DIL>
__device__ __forceinline__ void tile_work(
    float (*__restrict__ Stab)[SROW],
    int (*__restrict__ feats)[TF],
    const int* __restrict__ kbits,
    const float4* __restrict__ biasL4,
    const float4 (*__restrict__ kwL4)[3],
    const float* __restrict__ xb,
    int tid, int lane, int w, int P0)
{
    constexpr int LD = (DIL == 8) ? 3 : (DIL == 4) ? 2 : (DIL == 2) ? 1 : 0;
    constexpr int PS = (DIL == 1) ? 320 : (DIL == 2) ? 168 : (DIL == 4) ? 84 : 44;
    const int E0 = P0 - 32;

    // ---- build phase-major subset-sum tables (cross-lane producer) ----
    if (tid < TEXT) {
        const int e = tid;
        const int pos = E0 + e;
        float ch[8] = {0.f, 0.f, 0.f, 0.f, 0.f, 0.f, 0.f, 0.f};
        if (pos >= 0 && pos < TL) {
            const float4* xp = (const float4*)(xb + (size_t)pos * TC);
            const float4 a = xp[0], h = xp[1];
            ch[0] = a.x; ch[1] = a.y; ch[2] = a.z; ch[3] = a.w;
            ch[4] = h.x; ch[5] = h.y; ch[6] = h.z; ch[7] = h.w;
        }
        float lo[16], hi[16];
        lo[0] = 0.f; hi[0] = 0.f;
        #pragma unroll
        for (int m = 1; m < 16; ++m) lo[m] = lo[m & (m - 1)] + ch[__builtin_ctz(m)];
        #pragma unroll
        for (int m = 1; m < 16; ++m) hi[m] = hi[m & (m - 1)] + ch[4 + __builtin_ctz(m)];
        const int pe = (e & (DIL - 1)) * PS + (e >> LD);
        #pragma unroll
        for (int s = 0; s < 16; ++s) { Stab[s][pe] = lo[s]; Stab[16 + s][pe] = hi[s]; }
    }
    __syncthreads();

    // ---- per-wave: wave w owns kernels k = 8g + w ----
    const int p  = lane & (DIL - 1);
    const int jr = lane >> LD;
    const int f4b = p * (PS / 4) + (8 >> LD) - 1 + jr;

    unsigned long long mokI[4];
    #pragma unroll
    for (int i = 0; i < 4; ++i) {
        const int apos = P0 + p + (4 * jr + i) * DIL;
        mokI[i] = __ballot(apos >= 4 * DIL && apos < TL - 4 * DIL);
    }

    for (int g = 0; g < 10; g += 2) {
        const int k1 = g * 8 + w, k2 = k1 + 8;
        const int bb1 = kbits[k1], bb2 = kbits[k2];
        const float4* s1l = (const float4*)&Stab[bb1 & 15][0];
        const float4* s1h = (const float4*)&Stab[16 + (bb1 >> 4)][0];
        const float4* s2l = (const float4*)&Stab[bb2 & 15][0];
        const float4* s2h = (const float4*)&Stab[16 + (bb2 >> 4)][0];

        float4 A[3], H[3], A2[3], H2[3];
        #pragma unroll
        for (int j = 0; j < 3; ++j) { A[j] = s1l[f4b + j]; H[j] = s1h[f4b + j]; }
        #pragma unroll
        for (int j = 0; j < 3; ++j) { A2[j] = s2l[f4b + j]; H2[j] = s2h[f4b + j]; }

        float l1[12], l2[12];
        #pragma unroll
        for (int j = 0; j < 3; ++j) {
            l1[4*j+0] = A[j].x + H[j].x;  l1[4*j+1] = A[j].y + H[j].y;
            l1[4*j+2] = A[j].z + H[j].z;  l1[4*j+3] = A[j].w + H[j].w;
            l2[4*j+0] = A2[j].x + H2[j].x; l2[4*j+1] = A2[j].y + H2[j].y;
            l2[4*j+2] = A2[j].z + H2[j].z; l2[4*j+3] = A2[j].w + H2[j].w;
        }
        count_one(k1, l1, biasL4, kwL4, mokI, LD, feats, lane);
        count_one(k2, l2, biasL4, kwL4, mokI, LD, feats, lane);
    }
    // tail: kernels 80..83 on waves 0..3
    if (w < 4) {
        const int k = 80 + w;
        const int bb = kbits[k];
        const float4* sl = (const float4*)&Stab[bb & 15][0];
        const float4* sh = (const float4*)&Stab[16 + (bb >> 4)][0];
        float4 A[3], H[3];
        #pragma unroll
        for (int j = 0; j < 3; ++j) { A[j] = sl[f4b + j]; H[j] = sh[f4b + j]; }
        float l1[12];
        #pragma unroll
        for (int j = 0; j < 3; ++j) {
            l1[4*j+0] = A[j].x + H[j].x; l1[4*j+1] = A[j].y + H[j].y;
            l1[4*j+2] = A[j].z + H[j].z; l1[4*j+3] = A[j].w + H[j].w;
        }
        count_one(k, l1, biasL4, kwL4, mokI, LD, feats, lane);
    }
}

__global__ __launch_bounds__(512, 4) void mr_main(
    const float* __restrict__ x,      // [B, L, C]
    const float* __restrict__ kern,   // [K, 9]
    const float* __restrict__ cmask,  // [D, K, C]
    const float* __restrict__ bias,   // [D, K, F]
    const float* __restrict__ fstd,   // [NFEAT]
    float* __restrict__ out)          // [B, NFEAT], pre-init to -mean/std
{
    __shared__ __align__(16) float Stab[32][SROW];   // 45056 B
    __shared__ int   feats[TK][TF];
    __shared__ int   kbits[TK];
    __shared__ __align__(16) float4 biasL4[TK];
    __shared__ __align__(16) float4 kwL4[TK][3];

    const int bx = blockIdx.x;
    const int half = bx & 1, d_idx = (bx >> 1) & 3, b = bx >> 3;
    const int tid = threadIdx.x, lane = tid & 63, w = tid >> 6;
    const float* xb = x + (size_t)b * TL * TC;

    for (int kk = tid; kk < TK; kk += 512) {
        const float* cm = cmask + ((size_t)d_idx * TK + kk) * TC;
        int bits = 0;
        #pragma unroll
        for (int c = 0; c < TC; ++c) bits |= (cm[c] != 0.f) ? (1 << c) : 0;
        kbits[kk] = bits;
        const float* bp = bias + ((size_t)d_idx * TK + kk) * TF;
        biasL4[kk] = make_float4(bp[0], bp[1], bp[2], bp[3]);
        const float* kp = kern + kk * 9;
        kwL4[kk][0] = make_float4(kp[0], kp[1], kp[2], kp[3]);
        kwL4[kk][1] = make_float4(kp[4], kp[5], kp[6], kp[7]);
        kwL4[kk][2] = make_float4(kp[8], 0.f, 0.f, 0.f);
    }
    for (int i2 = tid; i2 < TK * TF; i2 += 512) ((int*)feats)[i2] = 0;
    // visibility: covered by the build->consume __syncthreads inside tile_work

    for (int t = 0; t < 4; ++t) {
        if (t) __syncthreads();   // prior tile's Stab readers done before rebuild
        const int P0 = half * 1024 + t * 256;
        switch (d_idx) {
            case 0:  tile_work<1>(Stab, feats, kbits, biasL4, kwL4, xb, tid, lane, w, P0); break;
            case 1:  tile_work<2>(Stab, feats, kbits, biasL4, kwL4, xb, tid, lane, w, P0); break;
            case 2:  tile_work<4>(Stab, feats, kbits, biasL4, kwL4, xb, tid, lane, w, P0); break;
            default: tile_work<8>(Stab, feats, kbits, biasL4, kwL4, xb, tid, lane, w, P0); break;
        }
    }

    __syncthreads();
    for (int idx = tid; idx < TK * TF; idx += 512) {
        const int k = idx >> 2;
        const bool odd2 = ((d_idx + k) & 1) != 0;
        const float denom = odd2 ? (float)(TL - (8 << d_idx)) : (float)TL;
        const int fid = d_idx * (TK * TF) + idx;
        const float scale = 1.0f / (denom * fstd[fid]);
        atomicAdd(&out[(size_t)b * NFEAT + fid], (float)feats[k][idx & 3] * scale);
    }
}

__global__ void mr_init(const float* __restrict__ fmean, const float* __restrict__ fstd,
                        float* __restrict__ out) {
    const int o = blockIdx.x * 256 + threadIdx.x;
    if (o < 64 * NFEAT) {
        const int fid = o % NFEAT;
        out[o] = -fmean[fid] / fstd[fid];
    }
}

extern "C" void kernel_launch(void* const* d_in, const int* in_sizes, int n_in,
                              void* d_out, int out_size, void* d_ws, size_t ws_size,
                              hipStream_t stream) {
    const float* x     = (const float*)d_in[0];
    const float* kern  = (const float*)d_in[1];
    const float* cmask = (const float*)d_in[2];
    const float* bias  = (const float*)d_in[3];
    const float* fmean = (const float*)d_in[4];
    const float* fstd  = (const float*)d_in[5];
    float* out = (float*)d_out;

    hipLaunchKernelGGL(mr_init, dim3((64 * NFEAT + 255) / 256), dim3(256), 0, stream,
                       fmean, fstd, out);
    hipLaunchKernelGGL(mr_main, dim3(64 * TD * 2), dim3(512), 0, stream,
                       x, kern, cmask, bias, fstd, out);
}